// Round 2
// baseline (43.072 us; speedup 1.0000x reference)
//
#include <hip/hip_runtime.h>
#include <hip/hip_bf16.h>

// Problem: B=16, N=256, F=64, H=64
// out[b,i,j] = (i==j) ? 1 : sigmoid( sum_h relu(a[b,i,h]+c[b,j,h]) * w2[h] + b2 )
// where a = hs @ w1[:, :64]^T + b1, c = hs @ w1[:, 64:]^T

#define BN 4096   // B*N
#define Fd 64
#define Hd 64
#define Nn 256

// ---------------- Kernel A: a (with b1 folded), c ----------------
// 4 rows per block, thread = (row, h). float4-vectorized loads.
__global__ __launch_bounds__(256) void prep_kernel(
    const float* __restrict__ hs, const float* __restrict__ w1,
    const float* __restrict__ b1,
    float* __restrict__ aout, float* __restrict__ cout) {
  __shared__ float4 hs_row[4][Fd / 4];

  const int lr = threadIdx.x >> 6;   // local row 0..3 (uniform per wave)
  const int h  = threadIdx.x & 63;
  const int row = blockIdx.x * 4 + lr;

  if (threadIdx.x < 64) {
    const int r = threadIdx.x >> 4, f4 = threadIdx.x & 15;
    hs_row[r][f4] = ((const float4*)(hs + (size_t)(blockIdx.x * 4 + r) * Fd))[f4];
  }
  __syncthreads();

  const float4* w1a = (const float4*)(w1 + (size_t)h * (2 * Fd));
  const float4* w1c = (const float4*)(w1 + (size_t)h * (2 * Fd) + Fd);

  float a = 0.f, c = 0.f;
#pragma unroll
  for (int f4 = 0; f4 < Fd / 4; ++f4) {
    const float4 x  = hs_row[lr][f4];   // wave-uniform LDS broadcast (b128)
    const float4 wa = w1a[f4];
    const float4 wc = w1c[f4];
    a = fmaf(x.x, wa.x, a); a = fmaf(x.y, wa.y, a);
    a = fmaf(x.z, wa.z, a); a = fmaf(x.w, wa.w, a);
    c = fmaf(x.x, wc.x, c); c = fmaf(x.y, wc.y, c);
    c = fmaf(x.z, wc.z, c); c = fmaf(x.w, wc.w, c);
  }
  aout[(size_t)row * Hd + h] = a + b1[h];
  cout[(size_t)row * Hd + h] = c;
}

// ---------------- Kernel B: pairwise logits + sigmoid ----------------
// Wave handles (b, j-tile of 64, 8 i-rows). lane = j offset.
// c-row per lane in 64 VGPRs; a-row and w2 wave-uniform -> SGPR s_loads.
// No LDS at all.
__global__ __launch_bounds__(256) void pair_kernel(
    const float* __restrict__ a_, const float* __restrict__ c_,
    const float* __restrict__ w2, const float* __restrict__ b2,
    float* __restrict__ out) {
  const int lane = threadIdx.x & 63;
  const int wv   = __builtin_amdgcn_readfirstlane(threadIdx.x >> 6);  // 0..3

  const int b  = blockIdx.z;
  const int j0 = blockIdx.y * 64;
  const int i0 = blockIdx.x * 32 + wv * 8;
  const int j  = j0 + lane;

  // Load this lane's c-row into registers (fully unrolled -> stays in VGPRs).
  const float4* crow4 = (const float4*)(c_ + (size_t)(b * Nn + j) * Hd);
  float cv[Hd];
#pragma unroll
  for (int h4 = 0; h4 < Hd / 4; ++h4) {
    const float4 t = crow4[h4];
    cv[4 * h4 + 0] = t.x; cv[4 * h4 + 1] = t.y;
    cv[4 * h4 + 2] = t.z; cv[4 * h4 + 3] = t.w;
  }

  const float bias2 = b2[0];

#pragma unroll
  for (int u = 0; u < 8; ++u) {
    const int i = i0 + u;
    // Wave-uniform a-row pointer -> scalar (SGPR) loads.
    const int arow_base = __builtin_amdgcn_readfirstlane(b * Nn + i);
    const float* arow = a_ + (size_t)arow_base * Hd;

    float acc = 0.f;
#pragma unroll
    for (int h = 0; h < Hd; ++h) {
      const float z = fmaxf(arow[h] + cv[h], 0.f);  // v_add(s,v) + v_max
      acc = fmaf(z, w2[h], acc);                    // v_fmac(v, s_w2)
    }

    const float logit = acc + bias2;
    const float s = 1.f / (1.f + __expf(-logit));
    out[(size_t)(b * Nn + i) * Nn + j] = (i == j) ? 1.0f : s;
  }
}

extern "C" void kernel_launch(void* const* d_in, const int* in_sizes, int n_in,
                              void* d_out, int out_size, void* d_ws, size_t ws_size,
                              hipStream_t stream) {
  const float* hs = (const float*)d_in[0];
  const float* w1 = (const float*)d_in[1];
  const float* b1 = (const float*)d_in[2];
  const float* w2 = (const float*)d_in[3];
  const float* b2 = (const float*)d_in[4];
  float* out = (float*)d_out;

  float* a_ws = (float*)d_ws;                  // BN*Hd floats = 1 MB
  float* c_ws = a_ws + (size_t)BN * Hd;        // 1 MB

  prep_kernel<<<BN / 4, 256, 0, stream>>>(hs, w1, b1, a_ws, c_ws);

  dim3 grid(Nn / 32, Nn / 64, 16);             // (i-tiles=8, j-tiles=4, b=16)
  pair_kernel<<<grid, 256, 0, stream>>>(a_ws, c_ws, w2, b2, out);
}

// Round 3
// 30.027 us; speedup vs baseline: 1.4344x; 1.4344x over previous
//
#include <hip/hip_runtime.h>
#include <hip/hip_bf16.h>

// Problem: B=16, N=256, F=64, H=64
// out[b,i,j] = (i==j) ? 1 : sigmoid( sum_h relu(a[b,i,h]+c[b,j,h]) * w2[h] + b2 )
// where a = hs @ w1[:, :64]^T + b1, c = hs @ w1[:, 64:]^T

#define BN 4096   // B*N
#define Fd 64
#define Hd 64
#define Nn 256

// ---------------- Kernel A: a (with b1 folded), c ----------------
// 4 rows per block, thread = (row, h). float4-vectorized everywhere.
__global__ __launch_bounds__(256) void prep_kernel(
    const float* __restrict__ hs, const float* __restrict__ w1,
    const float* __restrict__ b1,
    float* __restrict__ aout, float* __restrict__ cout) {
  __shared__ float4 hs4[4][Fd / 4];

  const int t  = threadIdx.x;
  const int lr = t >> 6;     // local row 0..3 (wave-uniform)
  const int h  = t & 63;
  const int row = blockIdx.x * 4 + lr;

  if (t < 64) {
    // 64 consecutive float4 = 1KB contiguous, coalesced
    hs4[t >> 4][t & 15] = ((const float4*)(hs + (size_t)blockIdx.x * 4 * Fd))[t];
  }
  __syncthreads();

  const float4* w1a = (const float4*)(w1 + (size_t)h * (2 * Fd));
  const float4* w1c = w1a + Fd / 4;

  float a = 0.f, c = 0.f;
#pragma unroll
  for (int f4 = 0; f4 < Fd / 4; ++f4) {
    const float4 x  = hs4[lr][f4];    // whole-wave LDS broadcast (b128)
    const float4 wa = w1a[f4];
    const float4 wc = w1c[f4];
    a = fmaf(x.x, wa.x, a); a = fmaf(x.y, wa.y, a);
    a = fmaf(x.z, wa.z, a); a = fmaf(x.w, wa.w, a);
    c = fmaf(x.x, wc.x, c); c = fmaf(x.y, wc.y, c);
    c = fmaf(x.z, wc.z, c); c = fmaf(x.w, wc.w, c);
  }
  aout[(size_t)row * Hd + h] = a + b1[h];
  cout[(size_t)row * Hd + h] = c;
}

// ---------------- Kernel B: pairwise logits + sigmoid ----------------
// 32x32 (i,j) tile per block, 256 threads, 4 outputs/thread.
// a/c tiles in LDS as float4[32][16] with XOR swizzle (q ^= r&15):
//   - enables ds_read_b128 (4x fewer LDS instrs than scalar)
//   - read cT4[jj][h4^(jj&15)]: each of 8 bank-quads gets exactly 8 lanes -> optimal
//   - aT4 reads are half-wave broadcasts
__global__ __launch_bounds__(256) void pair_kernel(
    const float* __restrict__ a_, const float* __restrict__ c_,
    const float* __restrict__ w2, const float* __restrict__ b2,
    float* __restrict__ out) {
  __shared__ float4 aT4[32][16];
  __shared__ float4 cT4[32][16];
  __shared__ float4 w2s4[16];

  const int b  = blockIdx.z;
  const int i0 = blockIdx.y * 32;
  const int j0 = blockIdx.x * 32;
  const int t  = threadIdx.x;

  // Stage both 32x64 tiles (512 float4 each), swizzled. Coalesced global reads.
#pragma unroll
  for (int p = 0; p < 2; ++p) {
    const int k = t + 256 * p;          // 0..511
    const int r = k >> 4, q = k & 15;
    const int qs = q ^ (r & 15);
    aT4[r][qs] = ((const float4*)(a_ + (size_t)(b * Nn + i0 + r) * Hd))[q];
    cT4[r][qs] = ((const float4*)(c_ + (size_t)(b * Nn + j0 + r) * Hd))[q];
  }
  if (t < 16) w2s4[t] = ((const float4*)w2)[t];
  __syncthreads();

  const float bias2 = b2[0];
  const int jj  = t & 31;
  const int ig  = t >> 5;         // 0..7 (wave-half-uniform)
  const int ii0 = ig << 2;

  float acc0 = 0.f, acc1 = 0.f, acc2 = 0.f, acc3 = 0.f;
#pragma unroll
  for (int h4 = 0; h4 < 16; ++h4) {
    const float4 cc = cT4[jj][h4 ^ (jj & 15)];
    const float4 ww = w2s4[h4];
    const float4 a0 = aT4[ii0 + 0][h4 ^ ((ii0 + 0) & 15)];
    const float4 a1 = aT4[ii0 + 1][h4 ^ ((ii0 + 1) & 15)];
    const float4 a2 = aT4[ii0 + 2][h4 ^ ((ii0 + 2) & 15)];
    const float4 a3 = aT4[ii0 + 3][h4 ^ ((ii0 + 3) & 15)];

    acc0 = fmaf(fmaxf(a0.x + cc.x, 0.f), ww.x, acc0);
    acc0 = fmaf(fmaxf(a0.y + cc.y, 0.f), ww.y, acc0);
    acc0 = fmaf(fmaxf(a0.z + cc.z, 0.f), ww.z, acc0);
    acc0 = fmaf(fmaxf(a0.w + cc.w, 0.f), ww.w, acc0);

    acc1 = fmaf(fmaxf(a1.x + cc.x, 0.f), ww.x, acc1);
    acc1 = fmaf(fmaxf(a1.y + cc.y, 0.f), ww.y, acc1);
    acc1 = fmaf(fmaxf(a1.z + cc.z, 0.f), ww.z, acc1);
    acc1 = fmaf(fmaxf(a1.w + cc.w, 0.f), ww.w, acc1);

    acc2 = fmaf(fmaxf(a2.x + cc.x, 0.f), ww.x, acc2);
    acc2 = fmaf(fmaxf(a2.y + cc.y, 0.f), ww.y, acc2);
    acc2 = fmaf(fmaxf(a2.z + cc.z, 0.f), ww.z, acc2);
    acc2 = fmaf(fmaxf(a2.w + cc.w, 0.f), ww.w, acc2);

    acc3 = fmaf(fmaxf(a3.x + cc.x, 0.f), ww.x, acc3);
    acc3 = fmaf(fmaxf(a3.y + cc.y, 0.f), ww.y, acc3);
    acc3 = fmaf(fmaxf(a3.z + cc.z, 0.f), ww.z, acc3);
    acc3 = fmaf(fmaxf(a3.w + cc.w, 0.f), ww.w, acc3);
  }

  const int j = j0 + jj;
  float accs[4] = {acc0, acc1, acc2, acc3};
#pragma unroll
  for (int u = 0; u < 4; ++u) {
    const int i = i0 + ii0 + u;
    const float logit = accs[u] + bias2;
    const float s = 1.f / (1.f + __expf(-logit));
    out[(size_t)(b * Nn + i) * Nn + j] = (i == j) ? 1.0f : s;
  }
}

extern "C" void kernel_launch(void* const* d_in, const int* in_sizes, int n_in,
                              void* d_out, int out_size, void* d_ws, size_t ws_size,
                              hipStream_t stream) {
  const float* hs = (const float*)d_in[0];
  const float* w1 = (const float*)d_in[1];
  const float* b1 = (const float*)d_in[2];
  const float* w2 = (const float*)d_in[3];
  const float* b2 = (const float*)d_in[4];
  float* out = (float*)d_out;

  float* a_ws = (float*)d_ws;                  // BN*Hd floats = 1 MB
  float* c_ws = a_ws + (size_t)BN * Hd;        // 1 MB

  prep_kernel<<<BN / 4, 256, 0, stream>>>(hs, w1, b1, a_ws, c_ws);

  dim3 grid(Nn / 32, Nn / 32, 16);             // (j-tiles, i-tiles, b)
  pair_kernel<<<grid, 256, 0, stream>>>(a_ws, c_ws, w2, b2, out);
}